// Round 12
// baseline (200.775 us; speedup 1.0000x reference)
//
#include <hip/hip_runtime.h>
#include <math.h>

// out layout: [ray_origins (N*M*3 f32)] [ray_dirs (N*M*3 f32)]
//
// Fill-shaped PERSISTENT SWEEP. Evidence: three structurally different
// kernels (1xf4/thread, nt-stores, 8xf4 deep bursts) all give identical
// ~76us kernel-component while the harness fill moves 768MiB at 6.7TB/s.
// Only remaining structural difference: the fill's waves grid-stride so the
// instantaneous write front is compact (<1MB) and advances monotonically
// (DRAM-row friendly); our kernels opened ~12-24k scattered 1KB fronts
// across the whole 201MB at once (row-activation bound).
//
// This version: 1024 blocks (4/CU, 16 waves/CU). Combined slot space
// [origins F4 | dirs F4], slot g = it*gridDim*256 + bid*256 + tid,
// 48 exact iterations. All waves sweep together: compact ~4MB front,
// origins pass (pure stores, fill-like) then dirs pass (compute+store).
// Camera constants cached in LDS (broadcast reads, camera uniform per wave
// since 196608 % 64 == 0). Plain stores (nt was neutral, R10).
typedef float f32x4 __attribute__((ext_vector_type(4)));

template <bool FAST3>
__global__ __launch_bounds__(256) void ray_sweep(
    const float* __restrict__ c2w,   // N*16 fp32
    const float* __restrict__ intr,  // N*9 fp32
    float* __restrict__ out,
    unsigned f4_per_cam,  // M*3/4 (196608 when FAST3)
    unsigned F4,          // N * f4_per_cam
    unsigned iters,       // 2*F4 / (gridDim.x*256), exact
    int N,
    int resShift,         // log2(res)
    float inv_res,
    size_t dir_off)       // N*M*3 floats
{
    extern __shared__ float cam[];   // N * 17 floats

    // one-time per-block camera cache: 12 rotation/origin + 5 intrinsics
    for (int c = threadIdx.x; c < N; c += 256) {
        const float* C = c2w + c * 16;
        const float* K = intr + c * 9;
        float* s = cam + c * 17;
        s[0]=C[0]; s[1]=C[1]; s[2]=C[2];  s[3]=C[3];
        s[4]=C[4]; s[5]=C[5]; s[6]=C[6];  s[7]=C[7];
        s[8]=C[8]; s[9]=C[9]; s[10]=C[10]; s[11]=C[11];
        s[12] = 1.0f / K[0];   // inv_fx
        s[13] = K[1];          // sk
        s[14] = K[2];          // cx
        s[15] = 1.0f / K[4];   // inv_fy
        s[16] = K[5];          // cy
    }
    __syncthreads();

    const unsigned gstride = gridDim.x * 256u;
    unsigned g = blockIdx.x * 256u + threadIdx.x;
    f32x4* o4 = reinterpret_cast<f32x4*>(out);
    f32x4* d4 = reinterpret_cast<f32x4*>(out + dir_off);
    const unsigned rmask = (1u << resShift) - 1u;

    for (unsigned it = 0; it < iters; ++it, g += gstride) {
        const bool isO = g < F4;            // wave-uniform (F4 % 64 == 0)
        const unsigned q = isO ? g : g - F4;            // slot within region
        const unsigned n = FAST3 ? ((q >> 16) / 3u)     // q/196608, exact
                                 : (q / f4_per_cam);
        const unsigned r = q - n * f4_per_cam;          // float4 within camera
        const unsigned f0 = r * 4u;
        const unsigned p0 = f0 / 3u;                    // magic-mul
        const unsigned ph = f0 - p0 * 3u;               // 0,1,2
        const float* s = cam + n * 17;                  // wave-uniform -> broadcast

        if (isO) {
            const float ox = s[3], oy = s[7], oz = s[11];
            const float ax = (ph == 0u) ? ox : ((ph == 1u) ? oy : oz);
            const float ay = (ph == 0u) ? oy : ((ph == 1u) ? oz : ox);
            const float az = (ph == 0u) ? oz : ((ph == 1u) ? ox : oy);
            const f32x4 vo = {ax, ay, az, ax};          // w==x all phases
            o4[g] = vo;
        } else {
            const float r00 = s[0], r01 = s[1], r02 = s[2];
            const float r10 = s[4], r11 = s[5], r12 = s[6];
            const float r20 = s[8], r21 = s[9], r22 = s[10];
            const float inv_fx = s[12], sk = s[13], cx = s[14];
            const float inv_fy = s[15], cy = s[16];

            float d0x, d0y, d0z, d1x, d1y, d1z;
            #pragma unroll
            for (int st = 0; st < 2; ++st) {
                const unsigned p = p0 + (unsigned)st;   // in-camera (region%4==0)
                const unsigned i = p >> resShift;
                const unsigned j = p & rmask;
                const float y_cam  = ((float)i + 0.5f) * inv_res;
                const float ycc    = (y_cam - cy) * inv_fy;
                const float y_lift = -ycc;
                const float xc_off = -cx - sk * ycc;
                const float x_cam  = ((float)j + 0.5f) * inv_res;
                const float x_lift = (x_cam + xc_off) * inv_fx;
                const float ux = fmaf(r00, x_lift, fmaf(r01, y_lift, -r02));
                const float uy = fmaf(r10, x_lift, fmaf(r11, y_lift, -r12));
                const float uz = fmaf(r20, x_lift, fmaf(r21, y_lift, -r22));
                const float ss  = fmaf(ux, ux, fmaf(uy, uy, uz * uz));
                const float inv = rsqrtf(fmaxf(ss, 1e-24f)); // = 1/max(norm,1e-12)
                if (st == 0) { d0x = ux*inv; d0y = uy*inv; d0z = uz*inv; }
                else         { d1x = ux*inv; d1y = uy*inv; d1z = uz*inv; }
            }
            f32x4 vd;
            vd.x = (ph == 0u) ? d0x : ((ph == 1u) ? d0y : d0z);
            vd.y = (ph == 0u) ? d0y : ((ph == 1u) ? d0z : d1x);
            vd.z = (ph == 0u) ? d0z : ((ph == 1u) ? d1x : d1y);
            vd.w = (ph == 0u) ? d1x : ((ph == 1u) ? d1y : d1z);
            d4[q] = vd;
        }
    }
}

extern "C" void kernel_launch(void* const* d_in, const int* in_sizes, int n_in,
                              void* d_out, int out_size, void* d_ws, size_t ws_size,
                              hipStream_t stream) {
    const float* c2w  = (const float*)d_in[0];   // fp32, N x 4 x 4
    const float* intr = (const float*)d_in[1];   // fp32, N x 3 x 3
    float* out = (float*)d_out;                  // fp32

    const int N = in_sizes[0] / 16;                                  // 32
    const long long M = (long long)out_size / (6LL * (long long)N);  // 262144
    const int res = (int)(sqrt((double)M) + 0.5);                    // 512

    int resShift = 0; while ((1 << resShift) < res) ++resShift;      // 9

    const long long F     = (long long)N * M * 3LL;     // floats per region
    const unsigned f4pc   = (unsigned)(M * 3LL / 4LL);  // 196608
    const unsigned F4     = (unsigned)N * f4pc;         // 6291456
    const size_t  dir_off = (size_t)F;

    // grid: 4 blocks/CU; shrink until it divides 2*F4 exactly
    unsigned grid = 1024;
    while ((2ull * F4) % ((unsigned long long)grid * 256ull) != 0ull && grid > 1)
        grid >>= 1;
    const unsigned iters = (unsigned)((2ull * F4) / ((unsigned long long)grid * 256ull));
    const size_t shmem = (size_t)N * 17 * sizeof(float);

    if (f4pc == 196608u) {
        ray_sweep<true><<<grid, 256, shmem, stream>>>(c2w, intr, out, f4pc, F4,
                                                      iters, N, resShift,
                                                      1.0f / (float)res, dir_off);
    } else {
        ray_sweep<false><<<grid, 256, shmem, stream>>>(c2w, intr, out, f4pc, F4,
                                                       iters, N, resShift,
                                                       1.0f / (float)res, dir_off);
    }
}